// Round 13
// baseline (3842.026 us; speedup 1.0000x reference)
//
#include <hip/hip_runtime.h>

#define NB 2048     // batch
#define NT 10000    // time points
#define NBLK 1024   // 2 trajectories per wave; 1024 one-wave blocks = 1 wave/SIMD

// Builtin-exact f16 types (clang AMDGPU builtins use __fp16 — R5 compile log)
typedef __fp16 half2_t __attribute__((ext_vector_type(2)));
typedef __fp16 half8_t __attribute__((ext_vector_type(8)));
typedef float  float4_t __attribute__((ext_vector_type(4)));

// DPP cross-lane (rows of 16): ~VALU-latency, no LDS pipe.
template <int CTRL>
__device__ __forceinline__ float dpp_f(float x) {
    return __int_as_float(__builtin_amdgcn_mov_dpp(__float_as_int(x), CTRL, 0xF, 0xF, true));
}
#define DPP_XOR1 0xB1   // quad_perm [1,0,3,2]
#define DPP_XOR2 0x4E   // quad_perm [2,3,0,1]
#define DPP_HMIR 0x141  // row_half_mirror
#define DPP_MIR  0x140  // row_mirror
#define DPP_BC15 0x142  // row_bcast15
#define DPP_BC31 0x143  // row_bcast31

__device__ __forceinline__ float readlane_f(float v, int l) {
    return __int_as_float(__builtin_amdgcn_readlane(__float_as_int(v), l));
}

__device__ __forceinline__ float fast_tanh_from_scaled(float pre_scaled) {
    // pre_scaled = 2*log2(e) * x  ->  tanh(x) = 1 - 2/(1 + e^{2x})
    float e = __builtin_amdgcn_exp2f(pre_scaled);
    return fmaf(-2.0f, __builtin_amdgcn_rcpf(1.0f + e), 1.0f);
}

// One wave = TWO trajectories (A,B), 1024 waves = 1 wave/SIMD on all 256 CUs.
// Each chain is the R11-proven step: MFMA-broadcast-reduce layer 2, unit-select
// layer 3, 6-stage DPP reduce + readlane. The two chains are independent ->
// in-wave ILP covers each chain's LDS/MFMA/DPP latency with the other's VALU.
// Weights (W2 frags, cb, w1/w3 consts) are shared; hbuf has disjoint regions.
__global__ __launch_bounds__(64, 1) void hybrid_euler_kernel(
    const float* __restrict__ z0in,
    const float* __restrict__ t,
    const float* __restrict__ prm,
    const float* __restrict__ W1,
    const float* __restrict__ b1,
    const float* __restrict__ W2,
    const float* __restrict__ b2,
    const float* __restrict__ W3,
    const float* __restrict__ b3,
    float* __restrict__ out)
{
    const int lane = threadIdx.x;        // one wave per block
    const int bp   = blockIdx.x;         // trajectory pair (2bp, 2bp+1)
    const int m    = lane & 15;          // C-col / A-row id
    const int kg   = lane >> 4;          // k-group (also this lane's N-tile)

    const float S = 2.8853900817779268f; // 2 * log2(e)

    // ---- layer-1 constants (unit = lane), shared by both chains ----
    const float w1a = W1[lane]      * S;
    const float w1b = W1[64 + lane] * S;
    const float b1v = b1[lane]      * S;

    // ---- W2 B-fragments (pre-scaled by S): 4 N-tiles x 2 K-frags, shared ----
    half8_t w2f[4][2];
    #pragma unroll
    for (int tile = 0; tile < 4; ++tile) {
        const int col = tile * 16 + m;
        #pragma unroll
        for (int h = 0; h < 2; ++h) {
            half8_t f;
            #pragma unroll
            for (int e = 0; e < 8; ++e) {
                const int k = h * 32 + kg * 8 + e;
                f[e] = (__fp16)(W2[k * 64 + col] * S);
            }
            w2f[tile][h] = f;
        }
    }

    // ---- loop-invariant bias quads (MFMA C-in; hoisted), shared ----
    float4_t cb[4];
    #pragma unroll
    for (int tile = 0; tile < 4; ++tile) {
        const float v = b2[tile * 16 + m] * S;
        float4_t q;
        q[0] = v; q[1] = v; q[2] = v; q[3] = v;
        cb[tile] = q;
    }

    // ---- layer-3 per-lane constants (unit = lane), shared ----
    const float w3v   = W3[lane];
    const float b3_64 = b3[0] * 0.015625f;  // b3/64: 64-lane reduce re-sums to b3
    const float kappa = prm[0];
    const float mass  = prm[2];
    const float kmoM  = -kappa / mass;

    // packed h1 pairs: chain A words 0..63, chain B words 64..127
    __shared__ alignas(16) int hbuf[128];

    // z-state for both chains (traj 2bp and 2bp+1 are adjacent: one float4)
    const float4 zi = *(const float4*)(z0in + bp * 4);
    float zA0 = zi.x, zA1 = zi.y, zB0 = zi.z, zB1 = zi.w;

    if (lane == 0) {
        *(float4*)(out + (size_t)bp * 4) = zi;
    }

    const int widx = (lane >> 1) + ((lane & 1) << 5);  // even->0..31, odd->32..63
    const bool kb0 = (lane & 16) != 0;
    const bool kb1 = (lane & 32) != 0;

    float tprev = t[0];
    float tcur  = t[1];
    float* optr = out + (size_t)NB * 2 + (size_t)bp * 4;

    for (int s = 1; s < NT; ++s) {
        const float tnext = (s + 1 < NT) ? t[s + 1] : tcur;
        const float dt = tcur - tprev;

        // ---- layer 1, both chains ----
        const float pre1A = fmaf(zA0, w1a, fmaf(zA1, w1b, b1v));
        const float pre1B = fmaf(zB0, w1a, fmaf(zB1, w1b, b1v));
        const float h1A = fast_tanh_from_scaled(pre1A);
        const float h1B = fast_tanh_from_scaled(pre1B);

        // ---- pack pairs via DPP quad swap ----
        const float h1An = dpp_f<DPP_XOR1>(h1A);
        const float h1Bn = dpp_f<DPP_XOR1>(h1B);
        const int hpiA = __builtin_bit_cast(int, __builtin_amdgcn_cvt_pkrtz(h1A, h1An));
        const int hpiB = __builtin_bit_cast(int, __builtin_amdgcn_cvt_pkrtz(h1B, h1Bn));

        // ---- broadcast through LDS: 2 writes + 4 broadcast ds_read_b128 ----
        hbuf[widx]      = hpiA;
        hbuf[64 + widx] = hpiB;
        asm volatile("" ::: "memory");   // pin write-before-read (wave lockstep)
        half8_t a0A, a1A, a0B, a1B;
        __builtin_memcpy(&a0A, &hbuf[kg * 4],           16);
        __builtin_memcpy(&a1A, &hbuf[16 + kg * 4],      16);
        __builtin_memcpy(&a0B, &hbuf[64 + kg * 4],      16);
        __builtin_memcpy(&a1B, &hbuf[64 + 16 + kg * 4], 16);

        // ---- layer 2: 8 MFMA per chain (4 N-tiles x 2 K-frags), bias C-in ----
        float4_t accA[4], accB[4];
        #pragma unroll
        for (int tile = 0; tile < 4; ++tile) {
            accA[tile] = __builtin_amdgcn_mfma_f32_16x16x32_f16(
                a1A, w2f[tile][1],
                __builtin_amdgcn_mfma_f32_16x16x32_f16(a0A, w2f[tile][0], cb[tile], 0, 0, 0),
                0, 0, 0);
            accB[tile] = __builtin_amdgcn_mfma_f32_16x16x32_f16(
                a1B, w2f[tile][1],
                __builtin_amdgcn_mfma_f32_16x16x32_f16(a0B, w2f[tile][0], cb[tile], 0, 0, 0),
                0, 0, 0);
        }

        // ---- layer 3, both chains: unit u = lane -> select acc[kg][0] ----
        const float a01A = kb0 ? accA[1][0] : accA[0][0];
        const float a23A = kb0 ? accA[3][0] : accA[2][0];
        const float a01B = kb0 ? accB[1][0] : accB[0][0];
        const float a23B = kb0 ? accB[3][0] : accB[2][0];
        const float pre2A = kb1 ? a23A : a01A;
        const float pre2B = kb1 ? a23B : a01B;
        const float h2A = fast_tanh_from_scaled(pre2A);
        const float h2B = fast_tanh_from_scaled(pre2B);
        float pA = fmaf(h2A, w3v, b3_64);
        float pB = fmaf(h2B, w3v, b3_64);

        // 6-stage reduce (R2-proven), chains interleaved for ILP
        pA += dpp_f<DPP_XOR1>(pA);  pB += dpp_f<DPP_XOR1>(pB);
        pA += dpp_f<DPP_XOR2>(pA);  pB += dpp_f<DPP_XOR2>(pB);
        pA += dpp_f<DPP_HMIR>(pA);  pB += dpp_f<DPP_HMIR>(pB);
        pA += dpp_f<DPP_MIR>(pA);   pB += dpp_f<DPP_MIR>(pB);
        pA += dpp_f<DPP_BC15>(pA);  pB += dpp_f<DPP_BC15>(pB);
        pA += dpp_f<DPP_BC31>(pA);  pB += dpp_f<DPP_BC31>(pB);
        const float nnA = readlane_f(pA, 63);
        const float nnB = readlane_f(pB, 63);

        // ---- Euler updates (z0n uses OLD z1; z1n uses OLD z0) ----
        const float zA1n = fmaf(dt, fmaf(kmoM, zA0, nnA), zA1);
        const float zA0n = fmaf(dt, zA1, zA0);
        const float zB1n = fmaf(dt, fmaf(kmoM, zB0, nnB), zB1);
        const float zB0n = fmaf(dt, zB1, zB0);
        zA0 = zA0n; zA1 = zA1n; zB0 = zB0n; zB1 = zB1n;

        if (lane == 0) {
            float4 st; st.x = zA0; st.y = zA1; st.z = zB0; st.w = zB1;
            *(float4*)optr = st;    // 16B coalesced: pair is adjacent in out
        }
        optr += (size_t)NB * 2;

        tprev = tcur;
        tcur  = tnext;
    }
}

extern "C" void kernel_launch(void* const* d_in, const int* in_sizes, int n_in,
                              void* d_out, int out_size, void* d_ws, size_t ws_size,
                              hipStream_t stream) {
    const float* z0 = (const float*)d_in[0];
    const float* t  = (const float*)d_in[1];
    const float* pp = (const float*)d_in[2];
    const float* W1 = (const float*)d_in[3];
    const float* b1 = (const float*)d_in[4];
    const float* W2 = (const float*)d_in[5];
    const float* b2 = (const float*)d_in[6];
    const float* W3 = (const float*)d_in[7];
    const float* b3 = (const float*)d_in[8];
    float* out = (float*)d_out;

    hybrid_euler_kernel<<<dim3(NBLK), dim3(64), 0, stream>>>(
        z0, t, pp, W1, b1, W2, b2, W3, b3, out);
}